// Round 14
// baseline (6981.544 us; speedup 1.0000x reference)
//
#include <hip/hip_runtime.h>
#include <cstdint>

// ---- problem dims ----
#define Hdim 512
#define Bdim 128
#define Tdim 512
#define FUT  32
#define TT   (Tdim + FUT)   // 544
#define NB1  32             // layer-1 GEMM blocks (16 units each)
#define NB2  64             // layer-2 GEMM blocks (8 units each, K=1024)
#define NBO  2              // trailing output blocks
#define NBLK (NB1 + NB2 + NBO)   // 98
#define RD   8              // h ring depth (parity & 7)
#define FSTR 32             // flag stride in u32 (one flag per 128-B line)

typedef _Float16 f16;
typedef f16   half8 __attribute__((ext_vector_type(8)));
typedef float f32x4 __attribute__((ext_vector_type(4)));
typedef unsigned long long ull;

// ---- ws layout (float offsets) ----
// AW1: [128 mt][16 ks][2 spl][64 lane][8] halfs   (A-fragments of packed W_hh1)
// AW2: [128 mt][32 ks][2 spl][64 lane][8] halfs   (packed [W_ih2 | W_hh2], K=1024)
// H planes: fragment-interleaved f16, 8-deep ring: [par 0..7][spl][(nt*16+ks)*64+lane][8]
#define AW1_OFF 0
#define AW2_OFF (AW1_OFF + 1048576)
#define B1P_OFF (AW2_OFF + 2097152)
#define B2P_OFF (B1P_OFF + 2048)
#define WX1_OFF (B2P_OFF + 2048)
#define XT_OFF  (WX1_OFF + 2048)      // [512 t][128 b] f32
#define H1P_OFF (XT_OFF + 65536)      // 8 par x 2 spl x 65536 f16 = 524288 floats
#define H2P_OFF (H1P_OFF + 524288)
#define ARR_OFF (H2P_OFF + 524288)    // padded flags: f1@i*32 (32), f2@(64+i)*32, fo@(128+i)*32
#define WS_FLOATS (ARR_OFF + 8192)

__device__ __forceinline__ float sigm(float v) { return 1.0f / (1.0f + __expf(-v)); }
__device__ __forceinline__ float tanh_fast(float v) {
    v = fminf(fmaxf(v, -20.0f), 20.0f);
    float e = __expf(2.0f * v);
    return (e - 1.0f) / (e + 1.0f);
}

__device__ __forceinline__ unsigned cohloadu(const unsigned* p) {
    return __hip_atomic_load(p, __ATOMIC_RELAXED, __HIP_MEMORY_SCOPE_AGENT);
}
__device__ __forceinline__ ull cohload64(const ull* p) {
    return __hip_atomic_load(p, __ATOMIC_RELAXED, __HIP_MEMORY_SCOPE_AGENT);
}
__device__ __forceinline__ void cohstore64(ull* p, ull v) {
    __hip_atomic_store(p, v, __ATOMIC_RELAXED, __HIP_MEMORY_SCOPE_AGENT);
}

union HB { ull u[2]; half8 h; };
// LLC-direct 16-B fragment load: TWO relaxed agent b64 atomics (R11/R13-proven).
// Relaxed atomics stay freely schedulable -> the 8-deep B-ring pipeline survives
// (R12's volatile dwordx4 serialized issue order -> 2.4x regression; never again).
__device__ __forceinline__ half8 fragload(const half8* p) {
    const ull* q = (const ull*)p;
    HB t; t.u[0] = cohload64(q); t.u[1] = cohload64(q + 1);
    return t.h;
}

// ---------- prep ----------
__global__ void lstm_prep(const float* __restrict__ x,
                          const float* __restrict__ W_ih1, const float* __restrict__ W_hh1,
                          const float* __restrict__ b_ih1, const float* __restrict__ b_hh1,
                          const float* __restrict__ W_ih2, const float* __restrict__ W_hh2,
                          const float* __restrict__ b_ih2, const float* __restrict__ b_hh2,
                          float* __restrict__ ws) {
    int i = blockIdx.x * blockDim.x + threadIdx.x;
    f16* aw1 = (f16*)(ws + AW1_OFF);
    f16* aw2 = (f16*)(ws + AW2_OFF);

    if (i < 131072) {                         // AW1
        int mt = i >> 10, rest = i & 1023, ks = rest >> 6, lane = rest & 63;
        int m = mt * 16 + (lane & 15);
        int u = m >> 2, g = m & 3;
        int kbase = ks * 32 + (lane >> 4) * 8;
        size_t ohi = ((((size_t)mt * 16 + ks) * 2 + 0) * 64 + lane) * 8;
        size_t olo = ((((size_t)mt * 16 + ks) * 2 + 1) * 64 + lane) * 8;
        #pragma unroll
        for (int j = 0; j < 8; ++j) {
            float wv = W_hh1[(size_t)(g * Hdim + u) * Hdim + kbase + j];
            f16 hi = (f16)wv;
            f16 lo = (f16)(wv - (float)hi);
            aw1[ohi + j] = hi; aw1[olo + j] = lo;
        }
    }
    if (i >= 131072 && i < 393216) {          // AW2 (K=1024 concat)
        int i2 = i - 131072;
        int mt = i2 >> 11, rest = i2 & 2047, ks = rest >> 6, lane = rest & 63;
        int m = mt * 16 + (lane & 15);
        int u = m >> 2, g = m & 3;
        int kbase = ks * 32 + (lane >> 4) * 8;
        size_t ohi = ((((size_t)mt * 32 + ks) * 2 + 0) * 64 + lane) * 8;
        size_t olo = ((((size_t)mt * 32 + ks) * 2 + 1) * 64 + lane) * 8;
        #pragma unroll
        for (int j = 0; j < 8; ++j) {
            int k = kbase + j;
            float wv = (k < Hdim) ? W_ih2[(size_t)(g * Hdim + u) * Hdim + k]
                                  : W_hh2[(size_t)(g * Hdim + u) * Hdim + (k - Hdim)];
            f16 hi = (f16)wv;
            f16 lo = (f16)(wv - (float)hi);
            aw2[ohi + j] = hi; aw2[olo + j] = lo;
        }
    }
    if (i < Hdim) {
        float4 bb1 = { b_ih1[i] + b_hh1[i],               b_ih1[Hdim+i] + b_hh1[Hdim+i],
                       b_ih1[2*Hdim+i] + b_hh1[2*Hdim+i], b_ih1[3*Hdim+i] + b_hh1[3*Hdim+i] };
        float4 bb2 = { b_ih2[i] + b_hh2[i],               b_ih2[Hdim+i] + b_hh2[Hdim+i],
                       b_ih2[2*Hdim+i] + b_hh2[2*Hdim+i], b_ih2[3*Hdim+i] + b_hh2[3*Hdim+i] };
        float4 wx  = { W_ih1[i], W_ih1[Hdim+i], W_ih1[2*Hdim+i], W_ih1[3*Hdim+i] };
        ((float4*)(ws + B1P_OFF))[i] = bb1;
        ((float4*)(ws + B2P_OFF))[i] = bb2;
        ((float4*)(ws + WX1_OFF))[i] = wx;
    }
    if (i < Tdim * Bdim) {
        int t = i >> 7, b = i & 127;
        ws[XT_OFF + i] = x[b * Tdim + t];
    }
    if (i < 262144) {                          // zero all 8 parities x 2 spl of h1,h2
        ((ull*)(ws + H1P_OFF))[i] = 0;
        ((ull*)(ws + H2P_OFF))[i] = 0;
    }
    if (i < 8192) ((unsigned*)(ws + ARR_OFF))[i] = 0u;
}

// ---------- persistent MFMA main kernel (fence-free, LLC-direct h path) ----------
__global__ __launch_bounds__(256, 1) void lstm_main(float* ws,
                                                    const float* __restrict__ Wout,
                                                    const float* __restrict__ bout,
                                                    float* __restrict__ out) {
    const int tid  = threadIdx.x, bid = blockIdx.x;
    const int w    = tid >> 6;
    const int lane = tid & 63;
    const int quad = lane >> 4;
    const int col  = lane & 15;
    const bool is1  = (bid < NB1);
    const bool is2  = (bid >= NB1) && (bid < NB1 + NB2);
    const bool isout = (bid >= NB1 + NB2);

    __shared__ f16   awlds[65536];       // 128 KB weight A-fragments
    __shared__ float wout_lds[Hdim];
    __shared__ float psum[2][128];
    __shared__ float xflds[128];
    __shared__ float qpart[4][64];
    __shared__ ull   hstg[1024];         // 8 KB coalesced-store staging

    unsigned* flg = (unsigned*)(ws + ARR_OFF);   // padded: f1@i*32, f2@(64+i)*32, fo@(128+i)*32
    unsigned short* stg = (unsigned short*)hstg;
    const float* xT = ws + XT_OFF;
    const float bout0 = bout[0];

    // ---- waits: poll padded flags (relaxed agent loads); no hardware fence needed
    auto wait1o = [&](unsigned T1, unsigned To) {       // f1 + out-ring guard
        if (tid < 64) {
            for (;;) {
                unsigned v1 = (lane < 32) ? cohloadu(flg + lane * FSTR)         : 0xFFFFFFFFu;
                unsigned vo = (lane < 2)  ? cohloadu(flg + (128 + lane) * FSTR) : 0xFFFFFFFFu;
                if (__all(v1 >= T1 && vo >= To)) break;
                __builtin_amdgcn_s_sleep(1);
            }
        }
        asm volatile("" ::: "memory");
        __syncthreads();
    };
    auto wait2 = [&](unsigned T2) {                     // f2 only (slim critical wait)
        if (tid < 64) {
            for (;;) {
                unsigned v2 = cohloadu(flg + (64 + lane) * FSTR);
                if (__all(v2 >= T2)) break;
                __builtin_amdgcn_s_sleep(1);
            }
        }
        asm volatile("" ::: "memory");
        __syncthreads();
    };
    auto wait3 = [&](unsigned T1, unsigned T2, unsigned To) {
        if (tid < 64) {
            const unsigned sent = 0xFFFFFFFFu;
            for (;;) {
                unsigned v1 = (lane < 32) ? cohloadu(flg + lane * FSTR)         : sent;
                unsigned v2 =               cohloadu(flg + (64 + lane) * FSTR);
                unsigned vo = (lane < 2)  ? cohloadu(flg + (128 + lane) * FSTR) : sent;
                if (__all(v1 >= T1 && v2 >= T2 && vo >= To)) break;
                __builtin_amdgcn_s_sleep(1);
            }
        }
        asm volatile("" ::: "memory");
        __syncthreads();
    };
    auto post = [&](unsigned* slot, unsigned val) {     // drain stores then own-line store
        __syncthreads();
        if (tid == 0)
            __hip_atomic_store(slot, val, __ATOMIC_RELAXED, __HIP_MEMORY_SCOPE_AGENT);
    };

    // fragment planes (8-deep ring)
    auto h1pf = [&](int par, int spl) {
        return (const half8*)((const unsigned short*)(ws + H1P_OFF) + (size_t)(par*2+spl) * 65536); };
    auto h2pf = [&](int par, int spl) {
        return (const half8*)((const unsigned short*)(ws + H2P_OFF) + (size_t)(par*2+spl) * 65536); };
    auto h1ull = [&](int par, int spl) {
        return (ull*)(ws + H1P_OFF) + (size_t)(par*2+spl) * 16384; };
    auto h2ull = [&](int par, int spl) {
        return (ull*)(ws + H2P_OFF) + (size_t)(par*2+spl) * 16384; };

    // ---- one-time: weight slice -> LDS
    if (!isout) {
        half8* d = (half8*)awlds;
        const half8* s = (const half8*)(ws + (is1 ? AW1_OFF : AW2_OFF))
                       + (size_t)(is1 ? bid : bid - NB1) * 8192;
        for (int i = tid; i < 8192; i += 256) d[i] = s[i];
    }
    wout_lds[tid]       = Wout[tid];
    wout_lds[256 + tid] = Wout[256 + tid];
    __syncthreads();
    const half8* aw8 = (const half8*)awlds;

    int b_[2] = { w * 32 + col, w * 32 + 16 + col };
    const int nt0 = 2 * w, nt1 = 2 * w + 1;
    int   u_[4];  float4 b1v[4], wxv[4];  float c1s[4][2];
    int   u2_[2]; float4 b2v[2];          float c2s[2][2];
    const int ks1 = bid >> 1, q0 = (bid & 1) * 2;            // G1 store geometry
    const int gid = bid - NB1;
    const int ks2 = gid >> 2, qg = gid & 3;                  // G2 store geometry
    if (is1) {
        #pragma unroll
        for (int mt = 0; mt < 4; ++mt) {
            u_[mt]  = bid * 16 + mt * 4 + quad;
            b1v[mt] = ((const float4*)(ws + B1P_OFF))[u_[mt]];
            wxv[mt] = ((const float4*)(ws + WX1_OFF))[u_[mt]];
            c1s[mt][0] = c1s[mt][1] = 0.0f;
        }
    } else if (is2) {
        #pragma unroll
        for (int mt = 0; mt < 2; ++mt) {
            u2_[mt] = gid * 8 + mt * 4 + quad;
            b2v[mt] = ((const float4*)(ws + B2P_OFF))[u2_[mt]];
            c2s[mt][0] = c2s[mt][1] = 0.0f;
        }
    }

    // ---- G1 coalesced publish: stage LDS -> 4 b64 agent stores/thread
    auto store1 = [&](int dpar) {
        __syncthreads();
        #pragma unroll
        for (int k = 0; k < 4; ++k) {
            int f = k * 256 + tid;                           // 0..1023 flat ull
            int spl = f >> 9, rest = f & 511, ntg = rest >> 6, pos = rest & 63;
            cohstore64(h1ull(dpar, spl) + ((ntg*16 + ks1)*64 + q0*16)*2 + pos, hstg[f]);
        }
    };
    auto stage1 = [&](int mt, int ntl, float hv) {
        f16 hhi = (f16)hv;
        f16 hlo = (f16)(hv - (float)hhi);
        int ntg = 2*w + ntl, mq = mt*4 + quad;
        int idx = ((ntg*32) + (mq>>3)*16 + col)*8 + (mq&7);
        stg[idx]        = __builtin_bit_cast(unsigned short, hhi);
        stg[2048 + idx] = __builtin_bit_cast(unsigned short, hlo);
    };

    // ---- layer-1 step ----
    auto gemm1 = [&](int spar, int dpar, float xv0, float xv1) {
        f32x4 acc[4][2] = {};
        const half8* fh = h1pf(spar, 0);
        const half8* fl = h1pf(spar, 1);
        half8 bh[8][2], bl[8][2];
        #pragma unroll
        for (int ks = 0; ks < 8; ++ks) {
            bh[ks][0] = fragload(fh + (nt0*16+ks)*64 + lane);
            bh[ks][1] = fragload(fh + (nt1*16+ks)*64 + lane);
            bl[ks][0] = fragload(fl + (nt0*16+ks)*64 + lane);
            bl[ks][1] = fragload(fl + (nt1*16+ks)*64 + lane);
        }
        #pragma unroll
        for (int ks = 0; ks < 16; ++ks) {
            half8 b0h = bh[ks&7][0], b1h = bh[ks&7][1];
            half8 b0l = bl[ks&7][0], b1l = bl[ks&7][1];
            if (ks < 8) {
                int kp = ks + 8;
                bh[ks&7][0] = fragload(fh + (nt0*16+kp)*64 + lane);
                bh[ks&7][1] = fragload(fh + (nt1*16+kp)*64 + lane);
                bl[ks&7][0] = fragload(fl + (nt0*16+kp)*64 + lane);
                bl[ks&7][1] = fragload(fl + (nt1*16+kp)*64 + lane);
            }
            #pragma unroll
            for (int mt = 0; mt < 4; ++mt) {
                half8 ah = aw8[((mt*16 + ks)*2 + 0)*64 + lane];
                half8 al = aw8[((mt*16 + ks)*2 + 1)*64 + lane];
                acc[mt][0] = __builtin_amdgcn_mfma_f32_16x16x32_f16(ah, b0h, acc[mt][0], 0, 0, 0);
                acc[mt][0] = __builtin_amdgcn_mfma_f32_16x16x32_f16(al, b0h, acc[mt][0], 0, 0, 0);
                acc[mt][0] = __builtin_amdgcn_mfma_f32_16x16x32_f16(ah, b0l, acc[mt][0], 0, 0, 0);
                acc[mt][1] = __builtin_amdgcn_mfma_f32_16x16x32_f16(ah, b1h, acc[mt][1], 0, 0, 0);
                acc[mt][1] = __builtin_amdgcn_mfma_f32_16x16x32_f16(al, b1h, acc[mt][1], 0, 0, 0);
                acc[mt][1] = __builtin_amdgcn_mfma_f32_16x16x32_f16(ah, b1l, acc[mt][1], 0, 0, 0);
            }
        }
        float xv[2] = { xv0, xv1 };
        #pragma unroll
        for (int mt = 0; mt < 4; ++mt)
            #pragma unroll
            for (int nt = 0; nt < 2; ++nt) {
                f32x4 g = acc[mt][nt];
                float pi = g[0] + b1v[mt].x + wxv[mt].x * xv[nt];
                float pf = g[1] + b1v[mt].y + wxv[mt].y * xv[nt];
                float pg = g[2] + b1v[mt].z + wxv[mt].z * xv[nt];
                float po = g[3] + b1v[mt].w + wxv[mt].w * xv[nt];
                float c = fmaf(sigm(pf), c1s[mt][nt], sigm(pi) * tanh_fast(pg));
                c1s[mt][nt] = c;
                stage1(mt, nt, sigm(po) * tanh_fast(c));
            }
        store1(dpar);
    };

    // ---- layer-2 step, phase-split across the f2 wait ----
    // Phase A (h1-half, ks 0..15) runs BEFORE the f2 wait: h1(s) is ring-protected
    // until THIS block posts f2=s+1, so pre-wait reads are safe. Phase B (h2-half,
    // ks 16..31) runs after f2 >= s. Halves the post-wait critical path.
    auto g2_step = [&](int s) {
        int cpar = s & 7, ppar = (s - 1) & 7;
        const half8* fh = h1pf(cpar, 0);
        const half8* fl = h1pf(cpar, 1);
        const half8* gh = h2pf(ppar, 0);
        const half8* gl = h2pf(ppar, 1);

        // ---- Phase A: h1-half (f1 + out-ring guard; both near-instant)
        wait1o((unsigned)(s + 1), (s >= RD) ? (unsigned)(s - (RD - 1)) : 0u);
        f32x4 acc[2][2] = {};
        {
            half8 bh[8][2], bl[8][2];
            #pragma unroll
            for (int ks = 0; ks < 8; ++ks) {
                bh[ks][0] = fragload(fh + (nt0*16+ks)*64 + lane);
                bh[ks][1] = fragload(fh + (nt1*16+ks)*64 + lane);
                bl[ks][0] = fragload(fl + (nt0*16+ks)*64 + lane);
                bl[ks][1] = fragload(fl + (nt1*16+ks)*64 + lane);
            }
            #pragma unroll
            for (int ks = 0; ks < 16; ++ks) {
                half8 b0h = bh[ks&7][0], b1h = bh[ks&7][1];
                half8 b0l = bl[ks&7][0], b1l = bl[ks&7][1];
                if (ks < 8) {
                    int kp = ks + 8;
                    bh[ks&7][0] = fragload(fh + (nt0*16+kp)*64 + lane);
                    bh[ks&7][1] = fragload(fh + (nt1*16+kp)*64 + lane);
                    bl[ks&7][0] = fragload(fl + (nt0*16+kp)*64 + lane);
                    bl[ks&7][1] = fragload(fl + (nt1*16+kp)*64 + lane);
                }
                #pragma unroll
                for (int mt = 0; mt < 2; ++mt) {
                    half8 ah = aw8[((mt*32 + ks)*2 + 0)*64 + lane];
                    half8 al = aw8[((mt*32 + ks)*2 + 1)*64 + lane];
                    acc[mt][0] = __builtin_amdgcn_mfma_f32_16x16x32_f16(ah, b0h, acc[mt][0], 0, 0, 0);
                    acc[mt][0] = __builtin_amdgcn_mfma_f32_16x16x32_f16(al, b0h, acc[mt][0], 0, 0, 0);
                    acc[mt][0] = __builtin_amdgcn_mfma_f32_16x16x32_f16(ah, b0l, acc[mt][0], 0, 0, 0);
                    acc[mt][1] = __builtin_amdgcn_mfma_f32_16x16x32_f16(ah, b1h, acc[mt][1], 0, 0, 0);
                    acc[mt][1] = __builtin_amdgcn_mfma_f32_16x16x32_f16(al, b1h, acc[mt][1], 0, 0, 0);
                    acc[mt][1] = __builtin_amdgcn_mfma_f32_16x16x32_f16(ah, b1l, acc[mt][1], 0, 0, 0);
                }
            }
        }

        // ---- Phase B: h2-half (the real recurrence wait; f2 only)
        wait2((unsigned)s);
        {
            half8 bh[8][2], bl[8][2];
            #pragma unroll
            for (int ks = 0; ks < 8; ++ks) {
                bh[ks][0] = fragload(gh + (nt0*16+ks)*64 + lane);
                bh[ks][1] = fragload(gh + (nt1*16+ks)*64 + lane);
                bl[ks][0] = fragload(gl + (nt0*16+ks)*64 + lane);
                bl[ks][1] = fragload(gl + (nt1*16+ks)*64 + lane);
            }
            #pragma unroll
            for (int kx = 0; kx < 16; ++kx) {
                int ks = kx + 16;                              // AW2 row (h2 half)
                half8 b0h = bh[kx&7][0], b1h = bh[kx&7][1];
                half8 b0l = bl[kx&7][0], b1l = bl[kx&7][1];
                if (kx < 8) {
                    int kp = kx + 8;
                    bh[kx&7][0] = fragload(gh + (nt0*16+kp)*64 + lane);
                    bh[kx&7][1] = fragload(gh + (nt1*16+kp)*64 + lane);
                    bl[kx&7][0] = fragload(gl + (nt0*16+kp)*64 + lane);
                    bl[kx&7][1] = fragload(gl + (nt1*16+kp)*64 + lane);
                }
                #pragma unroll
                for (int mt = 0; mt < 2; ++mt) {
                    half8 ah = aw8[((mt*32 + ks)*2 + 0)*64 + lane];
                    half8 al = aw8[((mt*32 + ks)*2 + 1)*64 + lane];
                    acc[mt][0] = __builtin_amdgcn_mfma_f32_16x16x32_f16(ah, b0h, acc[mt][0], 0, 0, 0);
                    acc[mt][0] = __builtin_amdgcn_mfma_f32_16x16x32_f16(al, b0h, acc[mt][0], 0, 0, 0);
                    acc[mt][0] = __builtin_amdgcn_mfma_f32_16x16x32_f16(ah, b0l, acc[mt][0], 0, 0, 0);
                    acc[mt][1] = __builtin_amdgcn_mfma_f32_16x16x32_f16(ah, b1h, acc[mt][1], 0, 0, 0);
                    acc[mt][1] = __builtin_amdgcn_mfma_f32_16x16x32_f16(al, b1h, acc[mt][1], 0, 0, 0);
                    acc[mt][1] = __builtin_amdgcn_mfma_f32_16x16x32_f16(ah, b1l, acc[mt][1], 0, 0, 0);
                }
            }
        }

        // epilogue: stage hi/lo then coalesced publish (2 b64 stores/thread)
        #pragma unroll
        for (int mt = 0; mt < 2; ++mt)
            #pragma unroll
            for (int nt = 0; nt < 2; ++nt) {
                f32x4 g = acc[mt][nt];
                float pi = g[0] + b2v[mt].x;
                float pf = g[1] + b2v[mt].y;
                float pg = g[2] + b2v[mt].z;
                float po = g[3] + b2v[mt].w;
                float c = fmaf(sigm(pf), c2s[mt][nt], sigm(pi) * tanh_fast(pg));
                c2s[mt][nt] = c;
                float hv = sigm(po) * tanh_fast(c);
                f16 hhi = (f16)hv;
                f16 hlo = (f16)(hv - (float)hhi);
                int ntg = 2*w + nt, mq = mt*4 + quad;
                int idx = ((ntg*16) + col)*8 + mq;
                stg[idx]        = __builtin_bit_cast(unsigned short, hhi);
                stg[1024 + idx] = __builtin_bit_cast(unsigned short, hlo);
            }
        __syncthreads();
        #pragma unroll
        for (int k = 0; k < 2; ++k) {
            int f = k * 256 + tid;                           // 0..511 flat ull
            int spl = f >> 8, rest = f & 255, ntg = rest >> 5, pos = rest & 31;
            cohstore64(h2ull(cpar, spl) + ((ntg*16 + ks2)*64 + qg*16)*2 + pos, hstg[f]);
        }
        post(&flg[(64 + gid) * FSTR], (unsigned)(s + 1));
    };

    // ================= GROUP 1 =================
    if (is1) {
        // prologue: h1(0) from x(0) (h1(-1)=0) -> parity 0
        #pragma unroll
        for (int mt = 0; mt < 4; ++mt)
            #pragma unroll
            for (int nt = 0; nt < 2; ++nt) {
                float xv = xT[b_[nt]];
                float pi = b1v[mt].x + wxv[mt].x * xv;
                float pg = b1v[mt].z + wxv[mt].z * xv;
                float po = b1v[mt].w + wxv[mt].w * xv;
                float c = sigm(pi) * tanh_fast(pg);
                c1s[mt][nt] = c;
                stage1(mt, nt, sigm(po) * tanh_fast(c));
            }
        store1(0);
        post(&flg[bid * FSTR], 1u);

        // main: step t publishes h1(t+1); f1 -> t+2
        for (int t = 0; t <= Tdim - 2; ++t) {
            wait3((unsigned)(t + 1), (t >= RD - 1) ? (unsigned)(t - (RD - 2)) : 0u, 0u);
            gemm1(t & 7, (t + 1) & 7,
                  xT[(t + 1) * Bdim + b_[0]], xT[(t + 1) * Bdim + b_[1]]);
            post(&flg[bid * FSTR], (unsigned)(t + 2));
        }

        // future: step t computes feedback O(t-1), publishes h1(t)
        for (int t = Tdim; t < TT; ++t) {
            wait3((unsigned)t, (unsigned)t, 0u);
            {
                int b = tid & 127, kh = tid >> 7;
                int nt = b >> 4, nl = b & 15;
                const half8* ph = h2pf((t - 1) & 7, 0);
                const half8* pl = h2pf((t - 1) & 7, 1);
                float a = 0.0f;
                #pragma unroll
                for (int kk = 0; kk < 8; ++kk) {
                    int ks = kh * 8 + kk;
                    #pragma unroll
                    for (int qd = 0; qd < 4; ++qd) {
                        half8 vh = fragload(ph + (nt*16+ks)*64 + qd*16 + nl);
                        half8 vl = fragload(pl + (nt*16+ks)*64 + qd*16 + nl);
                        int ub = ks*32 + qd*8;
                        #pragma unroll
                        for (int j = 0; j < 8; ++j)
                            a = fmaf((float)vh[j] + (float)vl[j], wout_lds[ub + j], a);
                    }
                }
                psum[kh][b] = a;
                __syncthreads();
                if (tid < 128) xflds[tid] = psum[0][tid] + psum[1][tid] + bout0;
                __syncthreads();
            }
            gemm1((t - 1) & 7, t & 7, xflds[b_[0]], xflds[b_[1]]);
            post(&flg[bid * FSTR], (unsigned)(t + 1));
        }
    }
    // ================= GROUP 2 =================
    else if (is2) {
        for (int s = 0; s < TT; ++s) g2_step(s);
    }
    // ================= OUT blocks =================
    else {
        int b = (bid - NB1 - NB2) * 64 + lane;
        int nt = b >> 4, nl = b & 15;
        for (int s = 0; s < TT; ++s) {
            wait2((unsigned)(s + 1));
            const half8* ph = h2pf(s & 7, 0);
            const half8* pl = h2pf(s & 7, 1);
            float a = 0.0f;
            #pragma unroll
            for (int kk = 0; kk < 4; ++kk) {
                int ks = w * 4 + kk;
                #pragma unroll
                for (int qd = 0; qd < 4; ++qd) {
                    half8 vh = fragload(ph + (nt*16+ks)*64 + qd*16 + nl);
                    half8 vl = fragload(pl + (nt*16+ks)*64 + qd*16 + nl);
                    int ub = ks*32 + qd*8;
                    #pragma unroll
                    for (int j = 0; j < 8; ++j)
                        a = fmaf((float)vh[j] + (float)vl[j], wout_lds[ub + j], a);
                }
            }
            qpart[w][lane] = a;
            __syncthreads();
            if (w == 0)
                out[(size_t)b * TT + s] = qpart[0][lane] + qpart[1][lane]
                                        + qpart[2][lane] + qpart[3][lane] + bout0;
            post(&flg[(128 + (bid - NB1 - NB2)) * FSTR], (unsigned)(s + 1));
        }
    }
}

extern "C" void kernel_launch(void* const* d_in, const int* in_sizes, int n_in,
                              void* d_out, int out_size, void* d_ws, size_t ws_size,
                              hipStream_t stream) {
    const float* x     = (const float*)d_in[0];
    const float* W_ih1 = (const float*)d_in[1];
    const float* W_hh1 = (const float*)d_in[2];
    const float* b_ih1 = (const float*)d_in[3];
    const float* b_hh1 = (const float*)d_in[4];
    const float* W_ih2 = (const float*)d_in[5];
    const float* W_hh2 = (const float*)d_in[6];
    const float* b_ih2 = (const float*)d_in[7];
    const float* b_hh2 = (const float*)d_in[8];
    const float* W_out = (const float*)d_in[9];
    const float* b_out = (const float*)d_in[10];
    float* ws  = (float*)d_ws;
    float* out = (float*)d_out;

    hipLaunchKernelGGL(lstm_prep, dim3(1536), dim3(256), 0, stream,
                       x, W_ih1, W_hh1, b_ih1, b_hh1, W_ih2, W_hh2, b_ih2, b_hh2, ws);
    hipLaunchKernelGGL(lstm_main, dim3(NBLK), dim3(256), 0, stream,
                       ws, W_out, b_out, out);
}

// Round 15
// 6027.886 us; speedup vs baseline: 1.1582x; 1.1582x over previous
//
#include <hip/hip_runtime.h>
#include <cstdint>

// ---- problem dims ----
#define Hdim 512
#define Bdim 128
#define Tdim 512
#define FUT  32
#define TT   (Tdim + FUT)   // 544
#define NB1  32             // layer-1 GEMM blocks (16 units each, full batch)
#define NB2  128            // layer-2 GEMM blocks (8 units x 64-batch half, K=1024)
#define NBO  2              // trailing output blocks
#define NBLK (NB1 + NB2 + NBO)   // 162
#define RD   8              // h ring depth (parity & 7)
#define FSTR 32             // flag stride in u32 (one flag per 128-B line)
// flag line bases: f1 @ 0..31, f2 @ 64..191, fo @ 200..201
#define F2B  64
#define FOB  200

typedef _Float16 f16;
typedef f16   half8 __attribute__((ext_vector_type(8)));
typedef float f32x4 __attribute__((ext_vector_type(4)));
typedef unsigned long long ull;

// ---- ws layout (float offsets) ----
// AW1: [128 mt][16 ks][2 spl][64 lane][8] halfs   (A-fragments of packed W_hh1)
// AW2: [128 mt][32 ks][2 spl][64 lane][8] halfs   (packed [W_ih2 | W_hh2], K=1024)
// H planes: fragment-interleaved f16, 8-deep ring: [par 0..7][spl][(nt*16+ks)*64+lane][8]
#define AW1_OFF 0
#define AW2_OFF (AW1_OFF + 1048576)
#define B1P_OFF (AW2_OFF + 2097152)
#define B2P_OFF (B1P_OFF + 2048)
#define WX1_OFF (B2P_OFF + 2048)
#define XT_OFF  (WX1_OFF + 2048)      // [512 t][128 b] f32
#define H1P_OFF (XT_OFF + 65536)      // 8 par x 2 spl x 65536 f16 = 524288 floats
#define H2P_OFF (H1P_OFF + 524288)
#define ARR_OFF (H2P_OFF + 524288)    // padded flags (8192 u32 = 256 lines)
#define WS_FLOATS (ARR_OFF + 8192)

__device__ __forceinline__ float sigm(float v) { return 1.0f / (1.0f + __expf(-v)); }
__device__ __forceinline__ float tanh_fast(float v) {
    v = fminf(fmaxf(v, -20.0f), 20.0f);
    float e = __expf(2.0f * v);
    return (e - 1.0f) / (e + 1.0f);
}

__device__ __forceinline__ unsigned cohloadu(const unsigned* p) {
    return __hip_atomic_load(p, __ATOMIC_RELAXED, __HIP_MEMORY_SCOPE_AGENT);
}
__device__ __forceinline__ ull cohload64(const ull* p) {
    return __hip_atomic_load(p, __ATOMIC_RELAXED, __HIP_MEMORY_SCOPE_AGENT);
}
__device__ __forceinline__ void cohstore64(ull* p, ull v) {
    __hip_atomic_store(p, v, __ATOMIC_RELAXED, __HIP_MEMORY_SCOPE_AGENT);
}

union HB { ull u[2]; half8 h; };
// LLC-direct 16-B fragment load: TWO relaxed agent b64 atomics (R11/R13-proven).
// Relaxed atomics stay schedulable -> deep B-ring pipeline survives (R12's
// volatile dwordx4 serialized issue order -> 2.4x regression; never again).
__device__ __forceinline__ half8 fragload(const half8* p) {
    const ull* q = (const ull*)p;
    HB t; t.u[0] = cohload64(q); t.u[1] = cohload64(q + 1);
    return t.h;
}

// ---------- prep (layouts unchanged) ----------
__global__ void lstm_prep(const float* __restrict__ x,
                          const float* __restrict__ W_ih1, const float* __restrict__ W_hh1,
                          const float* __restrict__ b_ih1, const float* __restrict__ b_hh1,
                          const float* __restrict__ W_ih2, const float* __restrict__ W_hh2,
                          const float* __restrict__ b_ih2, const float* __restrict__ b_hh2,
                          float* __restrict__ ws) {
    int i = blockIdx.x * blockDim.x + threadIdx.x;
    f16* aw1 = (f16*)(ws + AW1_OFF);
    f16* aw2 = (f16*)(ws + AW2_OFF);

    if (i < 131072) {                         // AW1
        int mt = i >> 10, rest = i & 1023, ks = rest >> 6, lane = rest & 63;
        int m = mt * 16 + (lane & 15);
        int u = m >> 2, g = m & 3;
        int kbase = ks * 32 + (lane >> 4) * 8;
        size_t ohi = ((((size_t)mt * 16 + ks) * 2 + 0) * 64 + lane) * 8;
        size_t olo = ((((size_t)mt * 16 + ks) * 2 + 1) * 64 + lane) * 8;
        #pragma unroll
        for (int j = 0; j < 8; ++j) {
            float wv = W_hh1[(size_t)(g * Hdim + u) * Hdim + kbase + j];
            f16 hi = (f16)wv;
            f16 lo = (f16)(wv - (float)hi);
            aw1[ohi + j] = hi; aw1[olo + j] = lo;
        }
    }
    if (i >= 131072 && i < 393216) {          // AW2 (K=1024 concat)
        int i2 = i - 131072;
        int mt = i2 >> 11, rest = i2 & 2047, ks = rest >> 6, lane = rest & 63;
        int m = mt * 16 + (lane & 15);
        int u = m >> 2, g = m & 3;
        int kbase = ks * 32 + (lane >> 4) * 8;
        size_t ohi = ((((size_t)mt * 32 + ks) * 2 + 0) * 64 + lane) * 8;
        size_t olo = ((((size_t)mt * 32 + ks) * 2 + 1) * 64 + lane) * 8;
        #pragma unroll
        for (int j = 0; j < 8; ++j) {
            int k = kbase + j;
            float wv = (k < Hdim) ? W_ih2[(size_t)(g * Hdim + u) * Hdim + k]
                                  : W_hh2[(size_t)(g * Hdim + u) * Hdim + (k - Hdim)];
            f16 hi = (f16)wv;
            f16 lo = (f16)(wv - (float)hi);
            aw2[ohi + j] = hi; aw2[olo + j] = lo;
        }
    }
    if (i < Hdim) {
        float4 bb1 = { b_ih1[i] + b_hh1[i],               b_ih1[Hdim+i] + b_hh1[Hdim+i],
                       b_ih1[2*Hdim+i] + b_hh1[2*Hdim+i], b_ih1[3*Hdim+i] + b_hh1[3*Hdim+i] };
        float4 bb2 = { b_ih2[i] + b_hh2[i],               b_ih2[Hdim+i] + b_hh2[Hdim+i],
                       b_ih2[2*Hdim+i] + b_hh2[2*Hdim+i], b_ih2[3*Hdim+i] + b_hh2[3*Hdim+i] };
        float4 wx  = { W_ih1[i], W_ih1[Hdim+i], W_ih1[2*Hdim+i], W_ih1[3*Hdim+i] };
        ((float4*)(ws + B1P_OFF))[i] = bb1;
        ((float4*)(ws + B2P_OFF))[i] = bb2;
        ((float4*)(ws + WX1_OFF))[i] = wx;
    }
    if (i < Tdim * Bdim) {
        int t = i >> 7, b = i & 127;
        ws[XT_OFF + i] = x[b * Tdim + t];
    }
    if (i < 262144) {                          // zero all 8 parities x 2 spl of h1,h2
        ((ull*)(ws + H1P_OFF))[i] = 0;
        ((ull*)(ws + H2P_OFF))[i] = 0;
    }
    if (i < 8192) ((unsigned*)(ws + ARR_OFF))[i] = 0u;
}

// ---------- persistent MFMA main kernel (fence-free, LLC-direct h path) ----------
__global__ __launch_bounds__(256, 1) void lstm_main(float* ws,
                                                    const float* __restrict__ Wout,
                                                    const float* __restrict__ bout,
                                                    float* __restrict__ out) {
    const int tid  = threadIdx.x, bid = blockIdx.x;
    const int w    = tid >> 6;
    const int lane = tid & 63;
    const int quad = lane >> 4;
    const int col  = lane & 15;
    const bool is1  = (bid < NB1);
    const bool is2  = (bid >= NB1) && (bid < NB1 + NB2);
    const bool isout = (bid >= NB1 + NB2);

    __shared__ f16   awlds[65536];       // 128 KB weight A-fragments
    __shared__ float wout_lds[Hdim];
    __shared__ float psum[2][128];
    __shared__ float xflds[128];
    __shared__ float qpart[4][64];
    __shared__ ull   hstg[1024];         // coalesced-store staging

    unsigned* flg = (unsigned*)(ws + ARR_OFF);
    unsigned short* stg = (unsigned short*)hstg;
    const float* xT = ws + XT_OFF;
    const float bout0 = bout[0];

    // ---- waits: poll padded flags (relaxed agent loads); no hardware fence
    auto wait1o = [&](unsigned T1, unsigned To) {       // f1(32) + fo(2)
        if (tid < 64) {
            for (;;) {
                unsigned v1 = (lane < 32) ? cohloadu(flg + lane * FSTR)         : 0xFFFFFFFFu;
                unsigned vo = (lane < 2)  ? cohloadu(flg + (FOB + lane) * FSTR) : 0xFFFFFFFFu;
                if (__all(v1 >= T1 && vo >= To)) break;
                __builtin_amdgcn_s_sleep(1);
            }
        }
        asm volatile("" ::: "memory");
        __syncthreads();
    };
    auto wait2f = [&](unsigned T2) {                    // f2(128) only
        if (tid < 64) {
            for (;;) {
                unsigned a = cohloadu(flg + (F2B + lane) * FSTR);
                unsigned b = cohloadu(flg + (F2B + 64 + lane) * FSTR);
                if (__all(a >= T2 && b >= T2)) break;
                __builtin_amdgcn_s_sleep(1);
            }
        }
        asm volatile("" ::: "memory");
        __syncthreads();
    };
    auto wait3 = [&](unsigned T1, unsigned T2) {        // f1(32) + f2(128)
        if (tid < 64) {
            for (;;) {
                unsigned v1 = (lane < 32) ? cohloadu(flg + lane * FSTR) : 0xFFFFFFFFu;
                unsigned a  = cohloadu(flg + (F2B + lane) * FSTR);
                unsigned b  = cohloadu(flg + (F2B + 64 + lane) * FSTR);
                if (__all(v1 >= T1 && a >= T2 && b >= T2)) break;
                __builtin_amdgcn_s_sleep(1);
            }
        }
        asm volatile("" ::: "memory");
        __syncthreads();
    };
    auto post = [&](unsigned* slot, unsigned val) {     // drain stores then own-line store
        __syncthreads();
        if (tid == 0)
            __hip_atomic_store(slot, val, __ATOMIC_RELAXED, __HIP_MEMORY_SCOPE_AGENT);
    };

    // fragment planes (8-deep ring)
    auto h1pf = [&](int par, int spl) {
        return (const half8*)((const unsigned short*)(ws + H1P_OFF) + (size_t)(par*2+spl) * 65536); };
    auto h2pf = [&](int par, int spl) {
        return (const half8*)((const unsigned short*)(ws + H2P_OFF) + (size_t)(par*2+spl) * 65536); };
    auto h1ull = [&](int par, int spl) {
        return (ull*)(ws + H1P_OFF) + (size_t)(par*2+spl) * 16384; };
    auto h2ull = [&](int par, int spl) {
        return (ull*)(ws + H2P_OFF) + (size_t)(par*2+spl) * 16384; };

    // ---- G2 geometry: 128 blocks = 64 unit-groups x 2 batch halves
    const int gid   = bid - NB1;                 // 0..127 for G2
    const int ug    = gid >> 1;                  // unit group 0..63 (8 units)
    const int bhalf = gid & 1;                   // batch half
    const int ntw   = bhalf * 4 + w;             // this wave's single nt (16 b cols)
    const int ks2   = ug >> 2, qg = ug & 3;      // h2 store geometry
    const int ks1   = bid >> 1, q0 = (bid & 1) * 2;  // G1 store geometry

    // ---- one-time: weight slice -> LDS
    if (is1) {
        half8* d = (half8*)awlds;
        const half8* s = (const half8*)(ws + AW1_OFF) + (size_t)bid * 8192;
        for (int i = tid; i < 8192; i += 256) d[i] = s[i];
    } else if (is2) {
        half8* d = (half8*)awlds;
        const half8* s = (const half8*)(ws + AW2_OFF) + (size_t)ug * 8192;
        for (int i = tid; i < 8192; i += 256) d[i] = s[i];
    }
    wout_lds[tid]       = Wout[tid];
    wout_lds[256 + tid] = Wout[256 + tid];
    __syncthreads();
    const half8* aw8 = (const half8*)awlds;

    int b_[2] = { w * 32 + col, w * 32 + 16 + col };
    const int nt0 = 2 * w, nt1 = 2 * w + 1;
    int   u_[4];  float4 b1v[4], wxv[4];  float c1s[4][2];
    int   u2_[2]; float4 b2v[2];          float c2s[2];
    if (is1) {
        #pragma unroll
        for (int mt = 0; mt < 4; ++mt) {
            u_[mt]  = bid * 16 + mt * 4 + quad;
            b1v[mt] = ((const float4*)(ws + B1P_OFF))[u_[mt]];
            wxv[mt] = ((const float4*)(ws + WX1_OFF))[u_[mt]];
            c1s[mt][0] = c1s[mt][1] = 0.0f;
        }
    } else if (is2) {
        #pragma unroll
        for (int mt = 0; mt < 2; ++mt) {
            u2_[mt] = ug * 8 + mt * 4 + quad;
            b2v[mt] = ((const float4*)(ws + B2P_OFF))[u2_[mt]];
            c2s[mt] = 0.0f;
        }
    }

    // ---- G1 coalesced publish: stage LDS -> 4 b64 agent stores/thread
    auto store1 = [&](int dpar) {
        __syncthreads();
        #pragma unroll
        for (int k = 0; k < 4; ++k) {
            int f = k * 256 + tid;
            int spl = f >> 9, rest = f & 511, ntg = rest >> 6, pos = rest & 63;
            cohstore64(h1ull(dpar, spl) + ((ntg*16 + ks1)*64 + q0*16)*2 + pos, hstg[f]);
        }
    };
    auto stage1 = [&](int mt, int ntl, float hv) {
        f16 hhi = (f16)hv;
        f16 hlo = (f16)(hv - (float)hhi);
        int ntg = 2*w + ntl, mq = mt*4 + quad;
        int idx = ((ntg*32) + (mq>>3)*16 + col)*8 + (mq&7);
        stg[idx]        = __builtin_bit_cast(unsigned short, hhi);
        stg[2048 + idx] = __builtin_bit_cast(unsigned short, hlo);
    };

    // ---- layer-1 step (unchanged from R13) ----
    auto gemm1 = [&](int spar, int dpar, float xv0, float xv1) {
        f32x4 acc[4][2] = {};
        const half8* fh = h1pf(spar, 0);
        const half8* fl = h1pf(spar, 1);
        half8 rh[8][2], rl[8][2];
        #pragma unroll
        for (int ks = 0; ks < 8; ++ks) {
            rh[ks][0] = fragload(fh + (nt0*16+ks)*64 + lane);
            rh[ks][1] = fragload(fh + (nt1*16+ks)*64 + lane);
            rl[ks][0] = fragload(fl + (nt0*16+ks)*64 + lane);
            rl[ks][1] = fragload(fl + (nt1*16+ks)*64 + lane);
        }
        #pragma unroll
        for (int ks = 0; ks < 16; ++ks) {
            half8 b0h = rh[ks&7][0], b1h = rh[ks&7][1];
            half8 b0l = rl[ks&7][0], b1l = rl[ks&7][1];
            if (ks < 8) {
                int kp = ks + 8;
                rh[ks&7][0] = fragload(fh + (nt0*16+kp)*64 + lane);
                rh[ks&7][1] = fragload(fh + (nt1*16+kp)*64 + lane);
                rl[ks&7][0] = fragload(fl + (nt0*16+kp)*64 + lane);
                rl[ks&7][1] = fragload(fl + (nt1*16+kp)*64 + lane);
            }
            #pragma unroll
            for (int mt = 0; mt < 4; ++mt) {
                half8 ah = aw8[((mt*16 + ks)*2 + 0)*64 + lane];
                half8 al = aw8[((mt*16 + ks)*2 + 1)*64 + lane];
                acc[mt][0] = __builtin_amdgcn_mfma_f32_16x16x32_f16(ah, b0h, acc[mt][0], 0, 0, 0);
                acc[mt][0] = __builtin_amdgcn_mfma_f32_16x16x32_f16(al, b0h, acc[mt][0], 0, 0, 0);
                acc[mt][0] = __builtin_amdgcn_mfma_f32_16x16x32_f16(ah, b0l, acc[mt][0], 0, 0, 0);
                acc[mt][1] = __builtin_amdgcn_mfma_f32_16x16x32_f16(ah, b1h, acc[mt][1], 0, 0, 0);
                acc[mt][1] = __builtin_amdgcn_mfma_f32_16x16x32_f16(al, b1h, acc[mt][1], 0, 0, 0);
                acc[mt][1] = __builtin_amdgcn_mfma_f32_16x16x32_f16(ah, b1l, acc[mt][1], 0, 0, 0);
            }
        }
        float xv[2] = { xv0, xv1 };
        #pragma unroll
        for (int mt = 0; mt < 4; ++mt)
            #pragma unroll
            for (int nt = 0; nt < 2; ++nt) {
                f32x4 g = acc[mt][nt];
                float pi = g[0] + b1v[mt].x + wxv[mt].x * xv[nt];
                float pf = g[1] + b1v[mt].y + wxv[mt].y * xv[nt];
                float pg = g[2] + b1v[mt].z + wxv[mt].z * xv[nt];
                float po = g[3] + b1v[mt].w + wxv[mt].w * xv[nt];
                float c = fmaf(sigm(pf), c1s[mt][nt], sigm(pi) * tanh_fast(pg));
                c1s[mt][nt] = c;
                stage1(mt, nt, sigm(po) * tanh_fast(c));
            }
        store1(dpar);
    };

    // ---- layer-2 step: R13 single-wait shape, halved per-wave stream (1 nt) ----
    auto g2_step = [&](int s) {
        int cpar = s & 7, ppar = (s - 1) & 7;
        const half8* fh = h1pf(cpar, 0);
        const half8* fl = h1pf(cpar, 1);
        const half8* gh = h2pf(ppar, 0);
        const half8* gl = h2pf(ppar, 1);

        wait1o((unsigned)(s + 1), (s >= RD) ? (unsigned)(s - (RD - 1)) : 0u);  // f1 + fo
        half8 rh[8], rl[8];
        #pragma unroll
        for (int ks = 0; ks < 8; ++ks) {            // prefetch h1-half first batch
            rh[ks] = fragload(fh + (ntw*16+ks)*64 + lane);
            rl[ks] = fragload(fl + (ntw*16+ks)*64 + lane);
        }
        wait2f((unsigned)s);                        // real wait: h2(s-1) complete

        f32x4 acc[2] = {};
        #pragma unroll
        for (int ks = 0; ks < 32; ++ks) {
            half8 b0h = rh[ks&7], b0l = rl[ks&7];
            if (ks < 24) {
                int kp = ks + 8;
                const half8* sh = (kp < 16) ? fh : gh;
                const half8* sl = (kp < 16) ? fl : gl;
                int kq = (kp < 16) ? kp : kp - 16;
                rh[ks&7] = fragload(sh + (ntw*16+kq)*64 + lane);
                rl[ks&7] = fragload(sl + (ntw*16+kq)*64 + lane);
            }
            #pragma unroll
            for (int mt = 0; mt < 2; ++mt) {
                half8 ah = aw8[((mt*32 + ks)*2 + 0)*64 + lane];
                half8 al = aw8[((mt*32 + ks)*2 + 1)*64 + lane];
                acc[mt] = __builtin_amdgcn_mfma_f32_16x16x32_f16(ah, b0h, acc[mt], 0, 0, 0);
                acc[mt] = __builtin_amdgcn_mfma_f32_16x16x32_f16(al, b0h, acc[mt], 0, 0, 0);
                acc[mt] = __builtin_amdgcn_mfma_f32_16x16x32_f16(ah, b0l, acc[mt], 0, 0, 0);
            }
        }
        // epilogue: stage hi/lo (LDS) then coalesced publish (1 b64 store/thread)
        #pragma unroll
        for (int mt = 0; mt < 2; ++mt) {
            f32x4 g = acc[mt];
            float pi = g[0] + b2v[mt].x;
            float pf = g[1] + b2v[mt].y;
            float pg = g[2] + b2v[mt].z;
            float po = g[3] + b2v[mt].w;
            float c = fmaf(sigm(pf), c2s[mt], sigm(pi) * tanh_fast(pg));
            c2s[mt] = c;
            float hv = sigm(po) * tanh_fast(c);
            f16 hhi = (f16)hv;
            f16 hlo = (f16)(hv - (float)hhi);
            int idx = ((w*16 + col)*8 + (mt*4 + quad));   // [ntl][col][j]
            stg[idx]       = __builtin_bit_cast(unsigned short, hhi);
            stg[512 + idx] = __builtin_bit_cast(unsigned short, hlo);
        }
        __syncthreads();
        {
            int f = tid;                                  // 0..255, 1 b64 each
            int spl = f >> 7, r = f & 127;
            int ntl = r >> 5, colp = (r >> 1) & 15, pos = r & 1;
            int nt = bhalf * 4 + ntl;
            cohstore64(h2ull(cpar, spl) + ((nt*16 + ks2)*64 + qg*16 + colp)*2 + pos, hstg[f]);
        }
        post(&flg[(F2B + gid) * FSTR], (unsigned)(s + 1));
    };

    // ================= GROUP 1 =================
    if (is1) {
        // prologue: h1(0) from x(0) (h1(-1)=0) -> parity 0
        #pragma unroll
        for (int mt = 0; mt < 4; ++mt)
            #pragma unroll
            for (int nt = 0; nt < 2; ++nt) {
                float xv = xT[b_[nt]];
                float pi = b1v[mt].x + wxv[mt].x * xv;
                float pg = b1v[mt].z + wxv[mt].z * xv;
                float po = b1v[mt].w + wxv[mt].w * xv;
                float c = sigm(pi) * tanh_fast(pg);
                c1s[mt][nt] = c;
                stage1(mt, nt, sigm(po) * tanh_fast(c));
            }
        store1(0);
        post(&flg[bid * FSTR], 1u);

        // main: step t publishes h1(t+1); f1 -> t+2
        for (int t = 0; t <= Tdim - 2; ++t) {
            wait3((unsigned)(t + 1), (t >= RD - 1) ? (unsigned)(t - (RD - 2)) : 0u);
            gemm1(t & 7, (t + 1) & 7,
                  xT[(t + 1) * Bdim + b_[0]], xT[(t + 1) * Bdim + b_[1]]);
            post(&flg[bid * FSTR], (unsigned)(t + 2));
        }

        // future: step t computes feedback O(t-1), publishes h1(t)
        for (int t = Tdim; t < TT; ++t) {
            wait3((unsigned)t, (unsigned)t);
            {
                int b = tid & 127, kh = tid >> 7;
                int nt = b >> 4, nl = b & 15;
                const half8* ph = h2pf((t - 1) & 7, 0);
                const half8* pl = h2pf((t - 1) & 7, 1);
                float a = 0.0f;
                #pragma unroll
                for (int kk = 0; kk < 8; ++kk) {
                    int ks = kh * 8 + kk;
                    #pragma unroll
                    for (int qd = 0; qd < 4; ++qd) {
                        half8 vh = fragload(ph + (nt*16+ks)*64 + qd*16 + nl);
                        half8 vl = fragload(pl + (nt*16+ks)*64 + qd*16 + nl);
                        int ub = ks*32 + qd*8;
                        #pragma unroll
                        for (int j = 0; j < 8; ++j)
                            a = fmaf((float)vh[j] + (float)vl[j], wout_lds[ub + j], a);
                    }
                }
                psum[kh][b] = a;
                __syncthreads();
                if (tid < 128) xflds[tid] = psum[0][tid] + psum[1][tid] + bout0;
                __syncthreads();
            }
            gemm1((t - 1) & 7, t & 7, xflds[b_[0]], xflds[b_[1]]);
            post(&flg[bid * FSTR], (unsigned)(t + 1));
        }
    }
    // ================= GROUP 2 =================
    else if (is2) {
        for (int s = 0; s < TT; ++s) g2_step(s);
    }
    // ================= OUT blocks =================
    else {
        int b = (bid - NB1 - NB2) * 64 + lane;
        int nt = b >> 4, nl = b & 15;
        for (int s = 0; s < TT; ++s) {
            wait2f((unsigned)(s + 1));
            const half8* ph = h2pf(s & 7, 0);
            const half8* pl = h2pf(s & 7, 1);
            float a = 0.0f;
            #pragma unroll
            for (int kk = 0; kk < 4; ++kk) {
                int ks = w * 4 + kk;
                #pragma unroll
                for (int qd = 0; qd < 4; ++qd) {
                    half8 vh = fragload(ph + (nt*16+ks)*64 + qd*16 + nl);
                    half8 vl = fragload(pl + (nt*16+ks)*64 + qd*16 + nl);
                    int ub = ks*32 + qd*8;
                    #pragma unroll
                    for (int j = 0; j < 8; ++j)
                        a = fmaf((float)vh[j] + (float)vl[j], wout_lds[ub + j], a);
                }
            }
            qpart[w][lane] = a;
            __syncthreads();
            if (w == 0)
                out[(size_t)b * TT + s] = qpart[0][lane] + qpart[1][lane]
                                        + qpart[2][lane] + qpart[3][lane] + bout0;
            post(&flg[(FOB + (bid - NB1 - NB2)) * FSTR], (unsigned)(s + 1));
        }
    }
}

extern "C" void kernel_launch(void* const* d_in, const int* in_sizes, int n_in,
                              void* d_out, int out_size, void* d_ws, size_t ws_size,
                              hipStream_t stream) {
    const float* x     = (const float*)d_in[0];
    const float* W_ih1 = (const float*)d_in[1];
    const float* W_hh1 = (const float*)d_in[2];
    const float* b_ih1 = (const float*)d_in[3];
    const float* b_hh1 = (const float*)d_in[4];
    const float* W_ih2 = (const float*)d_in[5];
    const float* W_hh2 = (const float*)d_in[6];
    const float* b_ih2 = (const float*)d_in[7];
    const float* b_hh2 = (const float*)d_in[8];
    const float* W_out = (const float*)d_in[9];
    const float* b_out = (const float*)d_in[10];
    float* ws  = (float*)d_ws;
    float* out = (float*)d_out;

    hipLaunchKernelGGL(lstm_prep, dim3(1536), dim3(256), 0, stream,
                       x, W_ih1, W_hh1, b_ih1, b_hh1, W_ih2, W_hh2, b_ih2, b_hh2, ws);
    hipLaunchKernelGGL(lstm_main, dim3(NBLK), dim3(256), 0, stream,
                       ws, W_out, b_out, out);
}

// Round 16
// 3871.454 us; speedup vs baseline: 1.8033x; 1.5570x over previous
//
#include <hip/hip_runtime.h>
#include <cstdint>

// ---- problem dims ----
#define Hdim 512
#define Bdim 128
#define Tdim 512
#define FUT  32
#define TT   (Tdim + FUT)   // 544
// Two independent batch-groups (A: cols 0-63 / nt 0-3, B: cols 64-127 / nt 4-7).
// All recurrences (h1, h2, out-feedback) are closed within a group.
#define NB1  64             // layer-1 blocks: 2 groups x 32 (16 units, 1 nt/wave)
#define NB2  128            // layer-2 blocks: 2 groups x 64 (8 units, 1 nt/wave)
#define NBO  2              // out blocks: 1 per group
#define NBLK (NB1 + NB2 + NBO)   // 194
#define RD   8              // h ring depth (parity & 7)
#define FSTR 32             // flag stride in u32 (one flag per 128-B line)
// flag line bases: f1 @ g*32 + i (lines 0..63), f2 @ 64 + g*64 + i (64..191), fo @ 200+g
#define F2B  64
#define FOB  200

typedef _Float16 f16;
typedef f16   half8 __attribute__((ext_vector_type(8)));
typedef float f32x4 __attribute__((ext_vector_type(4)));
typedef unsigned long long ull;

// ---- ws layout (float offsets) ----
#define AW1_OFF 0
#define AW2_OFF (AW1_OFF + 1048576)
#define B1P_OFF (AW2_OFF + 2097152)
#define B2P_OFF (B1P_OFF + 2048)
#define WX1_OFF (B2P_OFF + 2048)
#define XT_OFF  (WX1_OFF + 2048)      // [512 t][128 b] f32
#define H1P_OFF (XT_OFF + 65536)      // 8 par x 2 spl x 65536 f16 = 524288 floats
#define H2P_OFF (H1P_OFF + 524288)
#define ARR_OFF (H2P_OFF + 524288)    // padded flags (8192 u32 = 256 lines)
#define WS_FLOATS (ARR_OFF + 8192)

__device__ __forceinline__ float sigm(float v) { return 1.0f / (1.0f + __expf(-v)); }
__device__ __forceinline__ float tanh_fast(float v) {
    v = fminf(fmaxf(v, -20.0f), 20.0f);
    float e = __expf(2.0f * v);
    return (e - 1.0f) / (e + 1.0f);
}

__device__ __forceinline__ unsigned cohloadu(const unsigned* p) {
    return __hip_atomic_load(p, __ATOMIC_RELAXED, __HIP_MEMORY_SCOPE_AGENT);
}
__device__ __forceinline__ ull cohload64(const ull* p) {
    return __hip_atomic_load(p, __ATOMIC_RELAXED, __HIP_MEMORY_SCOPE_AGENT);
}
__device__ __forceinline__ void cohstore64(ull* p, ull v) {
    __hip_atomic_store(p, v, __ATOMIC_RELAXED, __HIP_MEMORY_SCOPE_AGENT);
}

union HB { ull u[2]; half8 h; };
// LLC-direct 16-B fragment load: TWO relaxed agent b64 atomics (R11/R13-proven,
// stays schedulable; R12's volatile variant serialized issue -> 2.4x regression).
__device__ __forceinline__ half8 fragload(const half8* p) {
    const ull* q = (const ull*)p;
    HB t; t.u[0] = cohload64(q); t.u[1] = cohload64(q + 1);
    return t.h;
}

// ---------- prep (layouts unchanged) ----------
__global__ void lstm_prep(const float* __restrict__ x,
                          const float* __restrict__ W_ih1, const float* __restrict__ W_hh1,
                          const float* __restrict__ b_ih1, const float* __restrict__ b_hh1,
                          const float* __restrict__ W_ih2, const float* __restrict__ W_hh2,
                          const float* __restrict__ b_ih2, const float* __restrict__ b_hh2,
                          float* __restrict__ ws) {
    int i = blockIdx.x * blockDim.x + threadIdx.x;
    f16* aw1 = (f16*)(ws + AW1_OFF);
    f16* aw2 = (f16*)(ws + AW2_OFF);

    if (i < 131072) {                         // AW1
        int mt = i >> 10, rest = i & 1023, ks = rest >> 6, lane = rest & 63;
        int m = mt * 16 + (lane & 15);
        int u = m >> 2, g = m & 3;
        int kbase = ks * 32 + (lane >> 4) * 8;
        size_t ohi = ((((size_t)mt * 16 + ks) * 2 + 0) * 64 + lane) * 8;
        size_t olo = ((((size_t)mt * 16 + ks) * 2 + 1) * 64 + lane) * 8;
        #pragma unroll
        for (int j = 0; j < 8; ++j) {
            float wv = W_hh1[(size_t)(g * Hdim + u) * Hdim + kbase + j];
            f16 hi = (f16)wv;
            f16 lo = (f16)(wv - (float)hi);
            aw1[ohi + j] = hi; aw1[olo + j] = lo;
        }
    }
    if (i >= 131072 && i < 393216) {          // AW2 (K=1024 concat)
        int i2 = i - 131072;
        int mt = i2 >> 11, rest = i2 & 2047, ks = rest >> 6, lane = rest & 63;
        int m = mt * 16 + (lane & 15);
        int u = m >> 2, g = m & 3;
        int kbase = ks * 32 + (lane >> 4) * 8;
        size_t ohi = ((((size_t)mt * 32 + ks) * 2 + 0) * 64 + lane) * 8;
        size_t olo = ((((size_t)mt * 32 + ks) * 2 + 1) * 64 + lane) * 8;
        #pragma unroll
        for (int j = 0; j < 8; ++j) {
            int k = kbase + j;
            float wv = (k < Hdim) ? W_ih2[(size_t)(g * Hdim + u) * Hdim + k]
                                  : W_hh2[(size_t)(g * Hdim + u) * Hdim + (k - Hdim)];
            f16 hi = (f16)wv;
            f16 lo = (f16)(wv - (float)hi);
            aw2[ohi + j] = hi; aw2[olo + j] = lo;
        }
    }
    if (i < Hdim) {
        float4 bb1 = { b_ih1[i] + b_hh1[i],               b_ih1[Hdim+i] + b_hh1[Hdim+i],
                       b_ih1[2*Hdim+i] + b_hh1[2*Hdim+i], b_ih1[3*Hdim+i] + b_hh1[3*Hdim+i] };
        float4 bb2 = { b_ih2[i] + b_hh2[i],               b_ih2[Hdim+i] + b_hh2[Hdim+i],
                       b_ih2[2*Hdim+i] + b_hh2[2*Hdim+i], b_ih2[3*Hdim+i] + b_hh2[3*Hdim+i] };
        float4 wx  = { W_ih1[i], W_ih1[Hdim+i], W_ih1[2*Hdim+i], W_ih1[3*Hdim+i] };
        ((float4*)(ws + B1P_OFF))[i] = bb1;
        ((float4*)(ws + B2P_OFF))[i] = bb2;
        ((float4*)(ws + WX1_OFF))[i] = wx;
    }
    if (i < Tdim * Bdim) {
        int t = i >> 7, b = i & 127;
        ws[XT_OFF + i] = x[b * Tdim + t];
    }
    if (i < 262144) {                          // zero all 8 parities x 2 spl of h1,h2
        ((ull*)(ws + H1P_OFF))[i] = 0;
        ((ull*)(ws + H2P_OFF))[i] = 0;
    }
    if (i < 8192) ((unsigned*)(ws + ARR_OFF))[i] = 0u;
}

// ---------- persistent MFMA main kernel (two independent batch-groups) ----------
__global__ __launch_bounds__(256, 1) void lstm_main(float* ws,
                                                    const float* __restrict__ Wout,
                                                    const float* __restrict__ bout,
                                                    float* __restrict__ out) {
    const int tid  = threadIdx.x, bid = blockIdx.x;
    const int w    = tid >> 6;
    const int lane = tid & 63;
    const int quad = lane >> 4;
    const int col  = lane & 15;
    const bool is1  = (bid < NB1);
    const bool is2  = (bid >= NB1) && (bid < NB1 + NB2);
    const bool isout = (bid >= NB1 + NB2);

    __shared__ f16   awlds[65536];       // 128 KB weight A-fragments
    __shared__ float wout_lds[Hdim];
    __shared__ float psum[4][64];
    __shared__ float xflds[64];
    __shared__ float qpart[4][64];
    __shared__ ull   hstg[512];          // coalesced-store staging

    unsigned* flg = (unsigned*)(ws + ARR_OFF);
    unsigned short* stg = (unsigned short*)hstg;
    const float* xT = ws + XT_OFF;
    const float bout0 = bout[0];

    // ---- group + role geometry
    const int bid1 = is1 ? (bid & 31) : 0;              // G1 index within group
    const int gid  = is2 ? (bid - NB1) : 0;             // 0..127
    const int ug   = gid & 63;                          // G2 unit-group
    const int gA   = is1 ? (bid >> 5) : (is2 ? (gid >> 6) : (bid - NB1 - NB2)); // batch group
    const int ntw  = gA * 4 + w;                        // this wave's nt (16 cols)
    const int ks1  = bid1 >> 1, qp0 = (bid1 & 1) * 2;   // G1 store geometry
    const int ks2  = ug >> 2,  qg  = ug & 3;            // G2 store geometry

    // ---- waits (group-local flag sets; s_sleep(4) throttles poll traffic)
    auto wait3 = [&](unsigned T1, unsigned T2) {        // f1g(32) + f2g(64)
        if (tid < 64) {
            for (;;) {
                unsigned v1 = (lane < 32) ? cohloadu(flg + (gA*32 + lane) * FSTR) : 0xFFFFFFFFu;
                unsigned v2 = cohloadu(flg + (F2B + gA*64 + lane) * FSTR);
                if (__all(v1 >= T1 && v2 >= T2)) break;
                __builtin_amdgcn_s_sleep(4);
            }
        }
        asm volatile("" ::: "memory");
        __syncthreads();
    };
    auto wait1o = [&](unsigned T1, unsigned To) {       // f1g(32) + fog(1)
        if (tid < 64) {
            for (;;) {
                unsigned v1 = (lane < 32) ? cohloadu(flg + (gA*32 + lane) * FSTR)  : 0xFFFFFFFFu;
                unsigned vo = (lane == 0) ? cohloadu(flg + (FOB + gA) * FSTR)      : 0xFFFFFFFFu;
                if (__all(v1 >= T1 && vo >= To)) break;
                __builtin_amdgcn_s_sleep(4);
            }
        }
        asm volatile("" ::: "memory");
        __syncthreads();
    };
    auto wait2f = [&](unsigned T2) {                    // f2g(64) only
        if (tid < 64) {
            for (;;) {
                unsigned v2 = cohloadu(flg + (F2B + gA*64 + lane) * FSTR);
                if (__all(v2 >= T2)) break;
                __builtin_amdgcn_s_sleep(4);
            }
        }
        asm volatile("" ::: "memory");
        __syncthreads();
    };
    auto post = [&](unsigned* slot, unsigned val) {     // drain stores then own-line store
        __syncthreads();
        if (tid == 0)
            __hip_atomic_store(slot, val, __ATOMIC_RELAXED, __HIP_MEMORY_SCOPE_AGENT);
    };

    // fragment planes (8-deep ring)
    auto h1pf = [&](int par, int spl) {
        return (const half8*)((const unsigned short*)(ws + H1P_OFF) + (size_t)(par*2+spl) * 65536); };
    auto h2pf = [&](int par, int spl) {
        return (const half8*)((const unsigned short*)(ws + H2P_OFF) + (size_t)(par*2+spl) * 65536); };
    auto h1ull = [&](int par, int spl) {
        return (ull*)(ws + H1P_OFF) + (size_t)(par*2+spl) * 16384; };
    auto h2ull = [&](int par, int spl) {
        return (ull*)(ws + H2P_OFF) + (size_t)(par*2+spl) * 16384; };

    // ---- one-time: weight slice -> LDS
    if (is1) {
        half8* d = (half8*)awlds;
        const half8* s = (const half8*)(ws + AW1_OFF) + (size_t)bid1 * 8192;
        for (int i = tid; i < 8192; i += 256) d[i] = s[i];
    } else if (is2) {
        half8* d = (half8*)awlds;
        const half8* s = (const half8*)(ws + AW2_OFF) + (size_t)ug * 8192;
        for (int i = tid; i < 8192; i += 256) d[i] = s[i];
    }
    wout_lds[tid]       = Wout[tid];
    wout_lds[256 + tid] = Wout[256 + tid];
    __syncthreads();
    const half8* aw8 = (const half8*)awlds;

    const int bcol = ntw * 16 + col;                    // this lane's batch column
    int   u_[4];  float4 b1v[4], wxv[4];  float c1s[4];
    int   u2_[2]; float4 b2v[2];          float c2s[2];
    if (is1) {
        #pragma unroll
        for (int mt = 0; mt < 4; ++mt) {
            u_[mt]  = bid1 * 16 + mt * 4 + quad;
            b1v[mt] = ((const float4*)(ws + B1P_OFF))[u_[mt]];
            wxv[mt] = ((const float4*)(ws + WX1_OFF))[u_[mt]];
            c1s[mt] = 0.0f;
        }
    } else if (is2) {
        #pragma unroll
        for (int mt = 0; mt < 2; ++mt) {
            u2_[mt] = ug * 8 + mt * 4 + quad;
            b2v[mt] = ((const float4*)(ws + B2P_OFF))[u2_[mt]];
            c2s[mt] = 0.0f;
        }
    }

    // ---- G1 staging + coalesced publish (2 b64 stores/thread)
    auto stage1 = [&](int mt, float hv) {
        f16 hhi = (f16)hv;
        f16 hlo = (f16)(hv - (float)hhi);
        int mq = mt*4 + quad, qp = mq >> 3, jj = mq & 7;
        int hi = ((w*2 + qp)*16 + col)*8 + jj;          // per-spl stride 1024 halfs
        stg[hi]        = __builtin_bit_cast(unsigned short, hhi);
        stg[1024 + hi] = __builtin_bit_cast(unsigned short, hlo);
    };
    auto store1 = [&](int dpar) {
        __syncthreads();
        #pragma unroll
        for (int k = 0; k < 2; ++k) {
            int f = k * 256 + tid;                      // 0..511 flat b64
            int spl = f >> 8, r = f & 255;
            int ntl = r >> 6, rr = r & 63;
            int qp = rr >> 5, r2 = rr & 31, colp = r2 >> 1, pos = r2 & 1;
            cohstore64(h1ull(dpar, spl)
                       + (((gA*4 + ntl)*16 + ks1)*64 + (qp0 + qp)*16 + colp)*2 + pos,
                       hstg[f]);
        }
    };

    // ---- layer-1 step (1 nt/wave) ----
    auto gemm1 = [&](int spar, int dpar, float xv) {
        f32x4 acc[4] = {};
        const half8* fh = h1pf(spar, 0);
        const half8* fl = h1pf(spar, 1);
        half8 rh[8], rl[8];
        #pragma unroll
        for (int ks = 0; ks < 8; ++ks) {
            rh[ks] = fragload(fh + (ntw*16+ks)*64 + lane);
            rl[ks] = fragload(fl + (ntw*16+ks)*64 + lane);
        }
        #pragma unroll
        for (int ks = 0; ks < 16; ++ks) {
            half8 b0h = rh[ks&7], b0l = rl[ks&7];
            if (ks < 8) {
                int kp = ks + 8;
                rh[ks&7] = fragload(fh + (ntw*16+kp)*64 + lane);
                rl[ks&7] = fragload(fl + (ntw*16+kp)*64 + lane);
            }
            #pragma unroll
            for (int mt = 0; mt < 4; ++mt) {
                half8 ah = aw8[((mt*16 + ks)*2 + 0)*64 + lane];
                half8 al = aw8[((mt*16 + ks)*2 + 1)*64 + lane];
                acc[mt] = __builtin_amdgcn_mfma_f32_16x16x32_f16(ah, b0h, acc[mt], 0, 0, 0);
                acc[mt] = __builtin_amdgcn_mfma_f32_16x16x32_f16(al, b0h, acc[mt], 0, 0, 0);
                acc[mt] = __builtin_amdgcn_mfma_f32_16x16x32_f16(ah, b0l, acc[mt], 0, 0, 0);
            }
        }
        #pragma unroll
        for (int mt = 0; mt < 4; ++mt) {
            f32x4 g = acc[mt];
            float pi = g[0] + b1v[mt].x + wxv[mt].x * xv;
            float pf = g[1] + b1v[mt].y + wxv[mt].y * xv;
            float pg = g[2] + b1v[mt].z + wxv[mt].z * xv;
            float po = g[3] + b1v[mt].w + wxv[mt].w * xv;
            float c = fmaf(sigm(pf), c1s[mt], sigm(pi) * tanh_fast(pg));
            c1s[mt] = c;
            stage1(mt, sigm(po) * tanh_fast(c));
        }
        store1(dpar);
    };

    // ---- layer-2 step (1 nt/wave; group-local waits) ----
    auto g2_step = [&](int s) {
        int cpar = s & 7, ppar = (s - 1) & 7;
        const half8* fh = h1pf(cpar, 0);
        const half8* fl = h1pf(cpar, 1);
        const half8* gh = h2pf(ppar, 0);
        const half8* gl = h2pf(ppar, 1);

        wait1o((unsigned)(s + 1), (s >= RD) ? (unsigned)(s - (RD - 1)) : 0u);  // f1g + fog
        half8 rh[8], rl[8];
        #pragma unroll
        for (int ks = 0; ks < 8; ++ks) {            // prefetch h1-half first batch
            rh[ks] = fragload(fh + (ntw*16+ks)*64 + lane);
            rl[ks] = fragload(fl + (ntw*16+ks)*64 + lane);
        }
        wait2f((unsigned)s);                        // real wait: group h2(s-1) complete

        f32x4 acc[2] = {};
        #pragma unroll
        for (int ks = 0; ks < 32; ++ks) {
            half8 b0h = rh[ks&7], b0l = rl[ks&7];
            if (ks < 24) {
                int kp = ks + 8;
                const half8* sh = (kp < 16) ? fh : gh;
                const half8* sl = (kp < 16) ? fl : gl;
                int kq = (kp < 16) ? kp : kp - 16;
                rh[ks&7] = fragload(sh + (ntw*16+kq)*64 + lane);
                rl[ks&7] = fragload(sl + (ntw*16+kq)*64 + lane);
            }
            #pragma unroll
            for (int mt = 0; mt < 2; ++mt) {
                half8 ah = aw8[((mt*32 + ks)*2 + 0)*64 + lane];
                half8 al = aw8[((mt*32 + ks)*2 + 1)*64 + lane];
                acc[mt] = __builtin_amdgcn_mfma_f32_16x16x32_f16(ah, b0h, acc[mt], 0, 0, 0);
                acc[mt] = __builtin_amdgcn_mfma_f32_16x16x32_f16(al, b0h, acc[mt], 0, 0, 0);
                acc[mt] = __builtin_amdgcn_mfma_f32_16x16x32_f16(ah, b0l, acc[mt], 0, 0, 0);
            }
        }
        // epilogue: stage hi/lo then coalesced publish (1 b64 store/thread)
        #pragma unroll
        for (int mt = 0; mt < 2; ++mt) {
            f32x4 g = acc[mt];
            float pi = g[0] + b2v[mt].x;
            float pf = g[1] + b2v[mt].y;
            float pg = g[2] + b2v[mt].z;
            float po = g[3] + b2v[mt].w;
            float c = fmaf(sigm(pf), c2s[mt], sigm(pi) * tanh_fast(pg));
            c2s[mt] = c;
            float hv = sigm(po) * tanh_fast(c);
            f16 hhi = (f16)hv;
            f16 hlo = (f16)(hv - (float)hhi);
            int idx = ((w*16 + col)*8 + (mt*4 + quad));
            stg[idx]       = __builtin_bit_cast(unsigned short, hhi);
            stg[512 + idx] = __builtin_bit_cast(unsigned short, hlo);
        }
        __syncthreads();
        {
            int f = tid;                            // 0..255, 1 b64 each
            int spl = f >> 7, r = f & 127;
            int ntl = r >> 5, colp = (r >> 1) & 15, pos = r & 1;
            int nt = gA * 4 + ntl;
            cohstore64(h2ull(cpar, spl) + ((nt*16 + ks2)*64 + qg*16 + colp)*2 + pos, hstg[f]);
        }
        post(&flg[(F2B + gA*64 + ug) * FSTR], (unsigned)(s + 1));
    };

    // ================= GROUP 1 =================
    if (is1) {
        // prologue: h1(0) from x(0) (h1(-1)=0) -> parity 0
        #pragma unroll
        for (int mt = 0; mt < 4; ++mt) {
            float xv = xT[bcol];
            float pi = b1v[mt].x + wxv[mt].x * xv;
            float pg = b1v[mt].z + wxv[mt].z * xv;
            float po = b1v[mt].w + wxv[mt].w * xv;
            float c = sigm(pi) * tanh_fast(pg);
            c1s[mt] = c;
            stage1(mt, sigm(po) * tanh_fast(c));
        }
        store1(0);
        post(&flg[(gA*32 + bid1) * FSTR], 1u);

        // main: step t publishes h1(t+1); f1 -> t+2
        for (int t = 0; t <= Tdim - 2; ++t) {
            wait3((unsigned)(t + 1), (t >= RD - 1) ? (unsigned)(t - (RD - 2)) : 0u);
            gemm1(t & 7, (t + 1) & 7, xT[(t + 1) * Bdim + bcol]);
            post(&flg[(gA*32 + bid1) * FSTR], (unsigned)(t + 2));
        }

        // future: step t computes group-local feedback O(t-1), publishes h1(t)
        for (int t = Tdim; t < TT; ++t) {
            wait3((unsigned)t, (unsigned)t);
            {   // cooperative O(t-1) for this group's 64 cols
                int bl = tid & 63, kh = tid >> 6;        // kh 0..3 -> 4 ks each
                int nt = gA * 4 + (bl >> 4), nl = bl & 15;
                const half8* ph = h2pf((t - 1) & 7, 0);
                const half8* pl = h2pf((t - 1) & 7, 1);
                float a = 0.0f;
                #pragma unroll
                for (int kk = 0; kk < 4; ++kk) {
                    int ks = kh * 4 + kk;
                    #pragma unroll
                    for (int qd = 0; qd < 4; ++qd) {
                        half8 vh = fragload(ph + (nt*16+ks)*64 + qd*16 + nl);
                        half8 vl = fragload(pl + (nt*16+ks)*64 + qd*16 + nl);
                        int ub = ks*32 + qd*8;
                        #pragma unroll
                        for (int j = 0; j < 8; ++j)
                            a = fmaf((float)vh[j] + (float)vl[j], wout_lds[ub + j], a);
                    }
                }
                psum[kh][bl] = a;
                __syncthreads();
                if (tid < 64)
                    xflds[tid] = psum[0][tid] + psum[1][tid] + psum[2][tid]
                               + psum[3][tid] + bout0;
                __syncthreads();
                if (bid1 == 0 && tid < 64 && (t - 1) >= Tdim)
                    out[(size_t)(gA*64 + tid) * TT + (t - 1)] = xflds[tid];
            }
            gemm1((t - 1) & 7, t & 7, xflds[bcol & 63]);
            post(&flg[(gA*32 + bid1) * FSTR], (unsigned)(t + 1));
        }
    }
    // ================= GROUP 2 =================
    else if (is2) {
        for (int s = 0; s < TT; ++s) g2_step(s);
    }
    // ================= OUT blocks (one per group) =================
    else {
        int b = gA * 64 + lane;
        int nt = b >> 4, nl = b & 15;
        for (int s = 0; s < TT; ++s) {
            wait2f((unsigned)(s + 1));
            const half8* ph = h2pf(s & 7, 0);
            const half8* pl = h2pf(s & 7, 1);
            float a = 0.0f;
            #pragma unroll
            for (int kk = 0; kk < 4; ++kk) {
                int ks = w * 4 + kk;
                #pragma unroll
                for (int qd = 0; qd < 4; ++qd) {
                    half8 vh = fragload(ph + (nt*16+ks)*64 + qd*16 + nl);
                    half8 vl = fragload(pl + (nt*16+ks)*64 + qd*16 + nl);
                    int ub = ks*32 + qd*8;
                    #pragma unroll
                    for (int j = 0; j < 8; ++j)
                        a = fmaf((float)vh[j] + (float)vl[j], wout_lds[ub + j], a);
                }
            }
            qpart[w][lane] = a;
            __syncthreads();
            if (w == 0)
                out[(size_t)b * TT + s] = qpart[0][lane] + qpart[1][lane]
                                        + qpart[2][lane] + qpart[3][lane] + bout0;
            post(&flg[(FOB + gA) * FSTR], (unsigned)(s + 1));
        }
    }
}

extern "C" void kernel_launch(void* const* d_in, const int* in_sizes, int n_in,
                              void* d_out, int out_size, void* d_ws, size_t ws_size,
                              hipStream_t stream) {
    const float* x     = (const float*)d_in[0];
    const float* W_ih1 = (const float*)d_in[1];
    const float* W_hh1 = (const float*)d_in[2];
    const float* b_ih1 = (const float*)d_in[3];
    const float* b_hh1 = (const float*)d_in[4];
    const float* W_ih2 = (const float*)d_in[5];
    const float* W_hh2 = (const float*)d_in[6];
    const float* b_ih2 = (const float*)d_in[7];
    const float* b_hh2 = (const float*)d_in[8];
    const float* W_out = (const float*)d_in[9];
    const float* b_out = (const float*)d_in[10];
    float* ws  = (float*)d_ws;
    float* out = (float*)d_out;

    hipLaunchKernelGGL(lstm_prep, dim3(1536), dim3(256), 0, stream,
                       x, W_ih1, W_hh1, b_ih1, b_hh1, W_ih2, W_hh2, b_ih2, b_hh2, ws);
    hipLaunchKernelGGL(lstm_main, dim3(NBLK), dim3(256), 0, stream,
                       ws, W_out, b_out, out);
}